// Round 14
// baseline (394.492 us; speedup 1.0000x reference)
//
#include <hip/hip_runtime.h>
#include <hip/hip_bf16.h>

#define N_NODES   100000
#define N_EDGES   1600000
#define IN_CH     128
#define HID       128
#define OUT_CH    2
#define NUM_GRAPHS 512

// counting-sort geometry: 512 nodes per bucket, 200 partition blocks x 8000 edges
#define BKT_SHIFT 9
#define NB2 ((N_NODES + 511) >> BKT_SHIFT)   // 196 buckets
#define PB  200                               // partition blocks
#define CHUNK (N_EDGES / PB)                  // 8000 edges per block (exact)

#define NCAST (N_NODES * IN_CH / 4 / 256)     // 12500 cast blocks

typedef __attribute__((ext_vector_type(8))) short bf16x8;
typedef __attribute__((ext_vector_type(4))) float f32x4;
typedef unsigned int uint32;
typedef unsigned long long uint64;

static __device__ __forceinline__ float b2f(uint32 b) {
    return __uint_as_float(b << 16);
}
static __device__ __forceinline__ unsigned short f2b(float f) {
    uint32 u = __float_as_uint(f);
    u += 0x7fffu + ((u >> 16) & 1u);   // round-to-nearest-even
    return (unsigned short)(u >> 16);
}
static __device__ __forceinline__ void acc8(float* a, int4 v) {
    uint32 x;
    x = (uint32)v.x; a[0] += __uint_as_float(x << 16); a[1] += __uint_as_float(x & 0xffff0000u);
    x = (uint32)v.y; a[2] += __uint_as_float(x << 16); a[3] += __uint_as_float(x & 0xffff0000u);
    x = (uint32)v.z; a[4] += __uint_as_float(x << 16); a[5] += __uint_as_float(x & 0xffff0000u);
    x = (uint32)v.w; a[6] += __uint_as_float(x << 16); a[7] += __uint_as_float(x & 0xffff0000u);
}

// ---- merged front kernel: cast | weight-prep | bucket histogram ----
__global__ void k_front(const float* __restrict__ x, unsigned short* __restrict__ h,
                        const float* w0, const float* w1, const float* w2,
                        const float* w3, const float* w4, const float* w5,
                        unsigned short* __restrict__ wt,
                        const int* __restrict__ dst, int* __restrict__ histG) {
    __shared__ int hist[NB2];
    int bid = blockIdx.x, t = threadIdx.x;
    if (bid < NCAST) {
        // cast x (f32) -> bf16, 4 elems/thread
        int base = (bid * 256 + t) * 4;
        float4 v = *(const float4*)(x + base);
        ushort4 o;
        o.x = f2b(v.x); o.y = f2b(v.y); o.z = f2b(v.z); o.w = f2b(v.w);
        *(ushort4*)(h + base) = o;
    } else if (bid < NCAST + 6) {
        // transpose + cast one 128x128 weight matrix
        const float* ws[6] = {w0, w1, w2, w3, w4, w5};
        int wi = bid - NCAST;
        const float* w = ws[wi];
        unsigned short* o = wt + wi * 16384;
        for (int i = t; i < 16384; i += 256) {
            int k = i >> 7, n = i & 127;
            o[n * 128 + k] = f2b(w[i]);
        }
    } else {
        // per-block LDS bucket histogram (no global atomics)
        int blk = bid - NCAST - 6;
        for (int i = t; i < NB2; i += 256) hist[i] = 0;
        __syncthreads();
        int base = blk * CHUNK;
        for (int i = t; i < CHUNK; i += 256)
            atomicAdd(&hist[dst[base + i] >> BKT_SHIFT], 1);
        __syncthreads();
        for (int i = t; i < NB2; i += 256) histG[i * PB + blk] = hist[i];
    }
}

// ---- two-level scan: stage 1 — per-block (1024 elems) local exclusive scan ----
__global__ void k_scan1(const int* __restrict__ in, int* __restrict__ out,
                        int* __restrict__ bsum, int n) {
    __shared__ int sm[256];
    int b = blockIdx.x, t = threadIdx.x;
    int base = b * 1024 + t * 4;
    int v0 = 0, v1 = 0, v2 = 0, v3 = 0;
    if (base + 3 < n) {
        int4 q = *(const int4*)(in + base);
        v0 = q.x; v1 = q.y; v2 = q.z; v3 = q.w;
    } else {
        if (base + 0 < n) v0 = in[base + 0];
        if (base + 1 < n) v1 = in[base + 1];
        if (base + 2 < n) v2 = in[base + 2];
        if (base + 3 < n) v3 = in[base + 3];
    }
    int s = v0 + v1 + v2 + v3;
    sm[t] = s;
    __syncthreads();
    for (int off = 1; off < 256; off <<= 1) {
        int u = (t >= off) ? sm[t - off] : 0;
        __syncthreads();
        sm[t] += u;
        __syncthreads();
    }
    int p = (t == 0) ? 0 : sm[t - 1];
    int o0 = p, o1 = p + v0, o2 = o1 + v1, o3 = o2 + v2;
    if (base + 3 < n) {
        *(int4*)(out + base) = make_int4(o0, o1, o2, o3);
    } else {
        if (base + 0 < n) out[base + 0] = o0;
        if (base + 1 < n) out[base + 1] = o1;
        if (base + 2 < n) out[base + 2] = o2;
        if (base + 3 < n) out[base + 3] = o3;
    }
    if (t == 255) bsum[b] = s + ((t == 0) ? 0 : sm[t - 1]);
}

// ---- stage 2+3 merged: each block locally prefixes bsum, adds in place ----
__global__ void k_scan3b(int* __restrict__ out, const int* __restrict__ bsum, int n) {
    __shared__ int add_s;
    int b = blockIdx.x, t = threadIdx.x;
    if (t == 0) {
        int s = 0;
        for (int i = 0; i < b; ++i) s += bsum[i];
        add_s = s;
    }
    __syncthreads();
    int add = add_s;
    int base = b * 1024 + t * 4;
    if (base + 3 < n) {
        int4 q = *(const int4*)(out + base);
        q.x += add; q.y += add; q.z += add; q.w += add;
        *(int4*)(out + base) = q;
    } else {
        for (int j = 0; j < 4; ++j)
            if (base + j < n) out[base + j] += add;
    }
}

// ---- p3 (+goff): partition edges into bucket-major pairs; LDS cursors only.
// blocks 0..PB-1: partition; blocks PB..PB+1: goff binary search (batch sorted).
__global__ void k_p3g(const int* __restrict__ ei, const int* __restrict__ baseG,
                      uint64* __restrict__ ebuf,
                      const int* __restrict__ batch, int* __restrict__ goff) {
    __shared__ int cur[NB2];
    int t = threadIdx.x, blk = blockIdx.x;
    if (blk >= PB) {
        int g = (blk - PB) * 512 + t;
        if (g <= NUM_GRAPHS) {
            int lo = 0, hi = N_NODES;
            while (lo < hi) {
                int mid = (lo + hi) >> 1;
                if (batch[mid] < g) lo = mid + 1; else hi = mid;
            }
            goff[g] = lo;
        }
        return;
    }
    for (int i = t; i < NB2; i += 512) cur[i] = baseG[i * PB + blk];
    __syncthreads();
    int base = blk * CHUNK;
    for (int i = t; i < CHUNK; i += 512) {
        int e = base + i;
        int src = ei[e];
        int dst = ei[N_EDGES + e];
        int pos = atomicAdd(&cur[dst >> BKT_SHIFT], 1);
        ebuf[pos] = ((uint64)(uint32)dst << 32) | (uint32)src;
    }
}

// ---- p4: one block per bucket — LDS degree count + scan, write off slice + csr ----
__global__ void k_p4(const uint64* __restrict__ ebuf, const int* __restrict__ baseG,
                     int* __restrict__ off, int* __restrict__ csr) {
    __shared__ int ldeg[512];
    __shared__ int lscan[512];
    __shared__ int lcur[512];
    int b = blockIdx.x, t = threadIdx.x;      // 512 threads
    int node0 = b << BKT_SHIFT;
    int nn = min(512, N_NODES - node0);
    int e0 = baseG[b * PB];
    int e1 = (b == NB2 - 1) ? N_EDGES : baseG[(b + 1) * PB];
    ldeg[t] = 0;
    __syncthreads();
    for (int e = e0 + t; e < e1; e += 512) {
        int dst = (int)(ebuf[e] >> 32);
        atomicAdd(&ldeg[dst - node0], 1);
    }
    __syncthreads();
    lscan[t] = ldeg[t];
    __syncthreads();
    for (int o = 1; o < 512; o <<= 1) {
        int v = (t >= o) ? lscan[t - o] : 0;
        __syncthreads();
        lscan[t] += v;
        __syncthreads();
    }
    int excl = (t == 0) ? 0 : lscan[t - 1];
    lcur[t] = e0 + excl;
    if (t < nn) off[node0 + t] = e0 + excl;
    if (b == NB2 - 1 && t == 0) off[N_NODES] = N_EDGES;
    __syncthreads();
    for (int e = e0 + t; e < e1; e += 512) {
        uint64 pr = ebuf[e];
        int dst = (int)(pr >> 32);
        int pos = atomicAdd(&lcur[dst - node0], 1);
        csr[pos] = (int)(pr & 0xffffffffu);
    }
}

// ---- fused GIN layer, 64-row blocks: agg->LDS, mm1 in-place, mm2 in-place, copy-out.
// 1563 blocks x 4 waves = ~24 waves/CU resident (vs R6's 128-row failure at 12).
template<int OUTER_RELU>
__global__ void k_gin(const unsigned short* __restrict__ h,
                      const int* __restrict__ off, const int* __restrict__ csr,
                      const unsigned short* __restrict__ w1t, const float* __restrict__ b1,
                      const unsigned short* __restrict__ w2t, const float* __restrict__ b2,
                      unsigned short* __restrict__ ho) {
    __shared__ unsigned short T[64 * 128];   // 16 KB, XOR-swizzled ((r&7)<<4 on byte addr)
    int tid = threadIdx.x;
    int lane = tid & 63, wave = tid >> 6;
    int l15 = lane & 15, l4 = lane >> 4;
    int row0 = blockIdx.x * 64;

    // ---- phase 1: aggregation. wave w handles tile rows w*16..w*16+15 (16 nodes).
    int g = l4, sub = l15;
    for (int r = wave * 16; r < wave * 16 + 16; ++r) {
        int node = row0 + r;
        if (node >= N_NODES) node = N_NODES - 1;   // tail clamp (rows never copied out)
        int e0 = off[node], e1 = off[node + 1];
        float a[8] = {0.f, 0.f, 0.f, 0.f, 0.f, 0.f, 0.f, 0.f};
        int e = e0 + g;
        for (; e + 12 < e1; e += 16) {             // 4 edges per group in flight
            int s0 = csr[e], s1 = csr[e + 4], s2 = csr[e + 8], s3 = csr[e + 12];
            int4 v0 = *(const int4*)(h + (size_t)s0 * 128 + sub * 8);
            int4 v1 = *(const int4*)(h + (size_t)s1 * 128 + sub * 8);
            int4 v2 = *(const int4*)(h + (size_t)s2 * 128 + sub * 8);
            int4 v3 = *(const int4*)(h + (size_t)s3 * 128 + sub * 8);
            acc8(a, v0); acc8(a, v1); acc8(a, v2); acc8(a, v3);
        }
        for (; e + 4 < e1; e += 8) {               // 2 in flight
            int s0 = csr[e], s1 = csr[e + 4];
            int4 v0 = *(const int4*)(h + (size_t)s0 * 128 + sub * 8);
            int4 v1 = *(const int4*)(h + (size_t)s1 * 128 + sub * 8);
            acc8(a, v0); acc8(a, v1);
        }
        if (e < e1) {
            int s0 = csr[e];
            int4 v0 = *(const int4*)(h + (size_t)s0 * 128 + sub * 8);
            acc8(a, v0);
        }
#pragma unroll
        for (int j = 0; j < 8; ++j) {
            a[j] += __shfl_xor(a[j], 16);
            a[j] += __shfl_xor(a[j], 32);
        }
        if (g == 0) {
            int4 sv = *(const int4*)(h + (size_t)node * 128 + sub * 8);
            acc8(a, sv);                           // + self
            int4 o;
            o.x = (int)((uint32)f2b(a[0]) | ((uint32)f2b(a[1]) << 16));
            o.y = (int)((uint32)f2b(a[2]) | ((uint32)f2b(a[3]) << 16));
            o.z = (int)((uint32)f2b(a[4]) | ((uint32)f2b(a[5]) << 16));
            o.w = (int)((uint32)f2b(a[6]) | ((uint32)f2b(a[7]) << 16));
            int byte = (r * 256 + sub * 16) ^ ((r & 7) << 4);
            *(int4*)((char*)T + byte) = o;
        }
    }
    __syncthreads();

    // ---- weight fragments for this wave's 32-col slice ----
    int wn0 = wave * 32;
    bf16x8 w1f[2][4], w2f[2][4];
#pragma unroll
    for (int nt = 0; nt < 2; ++nt)
#pragma unroll
        for (int k = 0; k < 4; ++k) {
            int o = (wn0 + nt * 16 + l15) * 128 + k * 32 + l4 * 8;
            w1f[nt][k] = *(const bf16x8*)(w1t + o);
            w2f[nt][k] = *(const bf16x8*)(w2t + o);
        }
    float bias1[2] = { b1[wn0 + l15], b1[wn0 + 16 + l15] };
    float bias2[2] = { b2[wn0 + l15], b2[wn0 + 16 + l15] };

    // ---- mm1: band-by-band in place (read band -> barrier -> write relu(A@W1+b1)) ----
#pragma unroll
    for (int mt = 0; mt < 4; ++mt) {
        int trow = mt * 16 + l15;
        int sw = (trow & 7) << 4;
        int rb = trow * 256 + l4 * 16;
        bf16x8 a0 = *(const bf16x8*)((const char*)T + ((rb + 0)   ^ sw));
        bf16x8 a1 = *(const bf16x8*)((const char*)T + ((rb + 64)  ^ sw));
        bf16x8 a2 = *(const bf16x8*)((const char*)T + ((rb + 128) ^ sw));
        bf16x8 a3 = *(const bf16x8*)((const char*)T + ((rb + 192) ^ sw));
        __syncthreads();   // all waves done reading band mt before anyone overwrites it
#pragma unroll
        for (int nt = 0; nt < 2; ++nt) {
            f32x4 acc = {0.f, 0.f, 0.f, 0.f};
            acc = __builtin_amdgcn_mfma_f32_16x16x32_bf16(a0, w1f[nt][0], acc, 0, 0, 0);
            acc = __builtin_amdgcn_mfma_f32_16x16x32_bf16(a1, w1f[nt][1], acc, 0, 0, 0);
            acc = __builtin_amdgcn_mfma_f32_16x16x32_bf16(a2, w1f[nt][2], acc, 0, 0, 0);
            acc = __builtin_amdgcn_mfma_f32_16x16x32_bf16(a3, w1f[nt][3], acc, 0, 0, 0);
#pragma unroll
            for (int j = 0; j < 4; ++j) {
                float v = fmaxf(acc[j] + bias1[nt], 0.f);
                int orow = mt * 16 + l4 * 4 + j;
                int ocol = wn0 + nt * 16 + l15;
                int byte = (orow * 256 + ocol * 2) ^ ((orow & 7) << 4);
                *(unsigned short*)((char*)T + byte) = f2b(v);
            }
        }
    }
    __syncthreads();

    // ---- mm2: band-by-band in place ----
#pragma unroll
    for (int mt = 0; mt < 4; ++mt) {
        int trow = mt * 16 + l15;
        int sw = (trow & 7) << 4;
        int rb = trow * 256 + l4 * 16;
        bf16x8 t0 = *(const bf16x8*)((const char*)T + ((rb + 0)   ^ sw));
        bf16x8 t1 = *(const bf16x8*)((const char*)T + ((rb + 64)  ^ sw));
        bf16x8 t2 = *(const bf16x8*)((const char*)T + ((rb + 128) ^ sw));
        bf16x8 t3 = *(const bf16x8*)((const char*)T + ((rb + 192) ^ sw));
        __syncthreads();
#pragma unroll
        for (int nt = 0; nt < 2; ++nt) {
            f32x4 acc = {0.f, 0.f, 0.f, 0.f};
            acc = __builtin_amdgcn_mfma_f32_16x16x32_bf16(t0, w2f[nt][0], acc, 0, 0, 0);
            acc = __builtin_amdgcn_mfma_f32_16x16x32_bf16(t1, w2f[nt][1], acc, 0, 0, 0);
            acc = __builtin_amdgcn_mfma_f32_16x16x32_bf16(t2, w2f[nt][2], acc, 0, 0, 0);
            acc = __builtin_amdgcn_mfma_f32_16x16x32_bf16(t3, w2f[nt][3], acc, 0, 0, 0);
#pragma unroll
            for (int j = 0; j < 4; ++j) {
                float v = acc[j] + bias2[nt];
                if (OUTER_RELU) v = fmaxf(v, 0.f);
                int orow = mt * 16 + l4 * 4 + j;
                int ocol = wn0 + nt * 16 + l15;
                int byte = (orow * 256 + ocol * 2) ^ ((orow & 7) << 4);
                *(unsigned short*)((char*)T + byte) = f2b(v);
            }
        }
    }
    __syncthreads();

    // ---- coalesced copy-out: 1024 16B chunks, 4 per thread ----
    for (int c = tid; c < 1024; c += 256) {
        int r = c >> 4, cc = c & 15;
        int byte = (r * 256 + cc * 16) ^ ((r & 7) << 4);
        int4 v = *(const int4*)((const char*)T + byte);
        int gr = row0 + r;
        if (gr < N_NODES)
            *(int4*)(ho + (size_t)gr * 128 + cc * 8) = v;
    }
}

// ---- per-graph mean pool + final linear: 4 waves per graph, LDS combine ----
__global__ void k_pool(const unsigned short* __restrict__ h,
                       const int* __restrict__ goff,
                       const float* __restrict__ wl, const float* __restrict__ bl,
                       float* __restrict__ out) {
    __shared__ float sm[4][64][2];
    int g = blockIdx.x;
    int tid = threadIdx.x;                 // 256 threads
    int wave = tid >> 6, lane = tid & 63;
    int e0 = goff[g], e1 = goff[g + 1];
    int c2 = lane << 1;
    float s0 = 0.f, s1 = 0.f;
    int r = e0 + wave;
    // 2 rows in flight per lane (rows r, r+4), stride 8
    for (; r + 4 < e1; r += 8) {
        uint32 v0 = *(const uint32*)(h + (size_t)r * 128 + c2);
        uint32 v1 = *(const uint32*)(h + (size_t)(r + 4) * 128 + c2);
        s0 += b2f(v0 & 0xffffu) + b2f(v1 & 0xffffu);
        s1 += b2f(v0 >> 16) + b2f(v1 >> 16);
    }
    if (r < e1) {
        uint32 v = *(const uint32*)(h + (size_t)r * 128 + c2);
        s0 += b2f(v & 0xffffu);
        s1 += b2f(v >> 16);
    }
    sm[wave][lane][0] = s0;
    sm[wave][lane][1] = s1;
    __syncthreads();
    if (wave == 0) {
        s0 = sm[0][lane][0] + sm[1][lane][0] + sm[2][lane][0] + sm[3][lane][0];
        s1 = sm[0][lane][1] + sm[1][lane][1] + sm[2][lane][1] + sm[3][lane][1];
        float inv = 1.f / fmaxf((float)(e1 - e0), 1.f);
        s0 *= inv; s1 *= inv;
        float o0 = s0 * wl[c2 * 2]     + s1 * wl[(c2 + 1) * 2];
        float o1 = s0 * wl[c2 * 2 + 1] + s1 * wl[(c2 + 1) * 2 + 1];
#pragma unroll
        for (int d = 32; d; d >>= 1) {
            o0 += __shfl_down(o0, d);
            o1 += __shfl_down(o1, d);
        }
        if (lane == 0) {
            out[g * 2]     = o0 + bl[0];
            out[g * 2 + 1] = o1 + bl[1];
        }
    }
}

extern "C" void kernel_launch(void* const* d_in, const int* in_sizes, int n_in,
                              void* d_out, int out_size, void* d_ws, size_t ws_size,
                              hipStream_t stream) {
    const float* x     = (const float*)d_in[0];
    const int*   ei    = (const int*)d_in[1];
    const int*   batch = (const int*)d_in[2];
    const float* w1[3] = {(const float*)d_in[3],  (const float*)d_in[7],  (const float*)d_in[11]};
    const float* b1[3] = {(const float*)d_in[4],  (const float*)d_in[8],  (const float*)d_in[12]};
    const float* w2[3] = {(const float*)d_in[5],  (const float*)d_in[9],  (const float*)d_in[13]};
    const float* b2[3] = {(const float*)d_in[6],  (const float*)d_in[10], (const float*)d_in[14]};
    const float* wl    = (const float*)d_in[15];
    const float* bl    = (const float*)d_in[16];

    char* p = (char*)d_ws;
    auto alloc = [&](size_t bytes) {
        char* r = p;
        p += (bytes + 255) & ~(size_t)255;
        return r;
    };
    int* off    = (int*)alloc((size_t)(N_NODES + 1) * 4);
    int* goff   = (int*)alloc((size_t)(NUM_GRAPHS + 1) * 4);
    int* histG  = (int*)alloc((size_t)(NB2 * PB) * 4);
    int* baseG  = (int*)alloc((size_t)(NB2 * PB + 1) * 4);
    int* bsum   = (int*)alloc((size_t)128 * 4);
    int* csr    = (int*)alloc((size_t)N_EDGES * 4);
    unsigned short* wts = (unsigned short*)alloc((size_t)6 * 16384 * 2);
    unsigned short* hA  = (unsigned short*)alloc((size_t)N_NODES * 128 * 2);
    unsigned short* hS  = (unsigned short*)alloc((size_t)N_NODES * 128 * 2);
    unsigned short* hB  = (unsigned short*)alloc((size_t)N_NODES * 128 * 2);
    uint64* ebuf = (uint64*)hS;   // alias: hS only used as CSR-build scratch now

    // ---- merged front: cast | wprep | p1 histogram ----
    k_front<<<NCAST + 6 + PB, 256, 0, stream>>>(x, hA,
        w1[0], w2[0], w1[1], w2[1], w1[2], w2[2], wts, ei + N_EDGES, histG);

    // ---- CSR build: block-binned counting sort, zero global atomics ----
    const int SCAN_N = NB2 * PB;                        // 39200
    const int SCAN_BLOCKS = (SCAN_N + 1023) / 1024;     // 39
    k_scan1<<<SCAN_BLOCKS, 256, 0, stream>>>(histG, baseG, bsum, SCAN_N);
    k_scan3b<<<SCAN_BLOCKS, 256, 0, stream>>>(baseG, bsum, SCAN_N);
    k_p3g<<<PB + 2, 512, 0, stream>>>(ei, baseG, ebuf, batch, goff);
    k_p4<<<NB2, 512, 0, stream>>>(ebuf, baseG, off, csr);

    unsigned short* wt1[3] = {wts,             wts + 2 * 16384, wts + 4 * 16384};
    unsigned short* wt2[3] = {wts + 1 * 16384, wts + 3 * 16384, wts + 5 * 16384};

    const int GIN_GRID = (N_NODES + 63) / 64;   // 1563 blocks, 64 nodes each

    // layer 0: hA -> hB
    k_gin<1><<<GIN_GRID, 256, 0, stream>>>(hA, off, csr, wt1[0], b1[0], wt2[0], b2[0], hB);
    // layer 1: hB -> hA
    k_gin<1><<<GIN_GRID, 256, 0, stream>>>(hB, off, csr, wt1[1], b1[1], wt2[1], b2[1], hA);
    // layer 2: hA -> hB (no outer relu)
    k_gin<0><<<GIN_GRID, 256, 0, stream>>>(hA, off, csr, wt1[2], b1[2], wt2[2], b2[2], hB);

    k_pool<<<NUM_GRAPHS, 256, 0, stream>>>(hB, goff, wl, bl, (float*)d_out);
}

// Round 15
// 327.947 us; speedup vs baseline: 1.2029x; 1.2029x over previous
//
#include <hip/hip_runtime.h>
#include <hip/hip_bf16.h>

#define N_NODES   100000
#define N_EDGES   1600000
#define IN_CH     128
#define HID       128
#define OUT_CH    2
#define NUM_GRAPHS 512

// counting-sort geometry: 512 nodes per bucket, 200 partition blocks x 8000 edges
#define BKT_SHIFT 9
#define NB2 ((N_NODES + 511) >> BKT_SHIFT)   // 196 buckets
#define PB  200                               // partition blocks
#define CHUNK (N_EDGES / PB)                  // 8000 edges per block (exact)

#define NCAST (N_NODES * IN_CH / 4 / 256)     // 12500 cast blocks

typedef __attribute__((ext_vector_type(8))) short bf16x8;
typedef __attribute__((ext_vector_type(4))) float f32x4;
typedef unsigned int uint32;
typedef unsigned long long uint64;

static __device__ __forceinline__ float b2f(uint32 b) {
    return __uint_as_float(b << 16);
}
static __device__ __forceinline__ unsigned short f2b(float f) {
    uint32 u = __float_as_uint(f);
    u += 0x7fffu + ((u >> 16) & 1u);   // round-to-nearest-even
    return (unsigned short)(u >> 16);
}
static __device__ __forceinline__ void acc8(float* a, int4 v) {
    uint32 x;
    x = (uint32)v.x; a[0] += __uint_as_float(x << 16); a[1] += __uint_as_float(x & 0xffff0000u);
    x = (uint32)v.y; a[2] += __uint_as_float(x << 16); a[3] += __uint_as_float(x & 0xffff0000u);
    x = (uint32)v.z; a[4] += __uint_as_float(x << 16); a[5] += __uint_as_float(x & 0xffff0000u);
    x = (uint32)v.w; a[6] += __uint_as_float(x << 16); a[7] += __uint_as_float(x & 0xffff0000u);
}

// ---- merged front kernel: cast | weight-prep | bucket histogram ----
__global__ void k_front(const float* __restrict__ x, unsigned short* __restrict__ h,
                        const float* w0, const float* w1, const float* w2,
                        const float* w3, const float* w4, const float* w5,
                        unsigned short* __restrict__ wt,
                        const int* __restrict__ dst, int* __restrict__ histG) {
    __shared__ int hist[NB2];
    int bid = blockIdx.x, t = threadIdx.x;
    if (bid < NCAST) {
        // cast x (f32) -> bf16, 4 elems/thread
        int base = (bid * 256 + t) * 4;
        float4 v = *(const float4*)(x + base);
        ushort4 o;
        o.x = f2b(v.x); o.y = f2b(v.y); o.z = f2b(v.z); o.w = f2b(v.w);
        *(ushort4*)(h + base) = o;
    } else if (bid < NCAST + 6) {
        // transpose + cast one 128x128 weight matrix
        const float* ws[6] = {w0, w1, w2, w3, w4, w5};
        int wi = bid - NCAST;
        const float* w = ws[wi];
        unsigned short* o = wt + wi * 16384;
        for (int i = t; i < 16384; i += 256) {
            int k = i >> 7, n = i & 127;
            o[n * 128 + k] = f2b(w[i]);
        }
    } else {
        // per-block LDS bucket histogram (no global atomics)
        int blk = bid - NCAST - 6;
        for (int i = t; i < NB2; i += 256) hist[i] = 0;
        __syncthreads();
        int base = blk * CHUNK;
        for (int i = t; i < CHUNK; i += 256)
            atomicAdd(&hist[dst[base + i] >> BKT_SHIFT], 1);
        __syncthreads();
        for (int i = t; i < NB2; i += 256) histG[i * PB + blk] = hist[i];
    }
}

// ---- two-level scan: stage 1 — per-block (1024 elems) local exclusive scan ----
__global__ void k_scan1(const int* __restrict__ in, int* __restrict__ out,
                        int* __restrict__ bsum, int n) {
    __shared__ int sm[256];
    int b = blockIdx.x, t = threadIdx.x;
    int base = b * 1024 + t * 4;
    int v0 = 0, v1 = 0, v2 = 0, v3 = 0;
    if (base + 3 < n) {
        int4 q = *(const int4*)(in + base);
        v0 = q.x; v1 = q.y; v2 = q.z; v3 = q.w;
    } else {
        if (base + 0 < n) v0 = in[base + 0];
        if (base + 1 < n) v1 = in[base + 1];
        if (base + 2 < n) v2 = in[base + 2];
        if (base + 3 < n) v3 = in[base + 3];
    }
    int s = v0 + v1 + v2 + v3;
    sm[t] = s;
    __syncthreads();
    for (int off = 1; off < 256; off <<= 1) {
        int u = (t >= off) ? sm[t - off] : 0;
        __syncthreads();
        sm[t] += u;
        __syncthreads();
    }
    int p = (t == 0) ? 0 : sm[t - 1];
    int o0 = p, o1 = p + v0, o2 = o1 + v1, o3 = o2 + v2;
    if (base + 3 < n) {
        *(int4*)(out + base) = make_int4(o0, o1, o2, o3);
    } else {
        if (base + 0 < n) out[base + 0] = o0;
        if (base + 1 < n) out[base + 1] = o1;
        if (base + 2 < n) out[base + 2] = o2;
        if (base + 3 < n) out[base + 3] = o3;
    }
    if (t == 255) bsum[b] = s + ((t == 0) ? 0 : sm[t - 1]);
}

// ---- stage 2+3 merged: each block locally prefixes bsum, adds in place ----
__global__ void k_scan3b(int* __restrict__ out, const int* __restrict__ bsum, int n) {
    __shared__ int add_s;
    int b = blockIdx.x, t = threadIdx.x;
    if (t == 0) {
        int s = 0;
        for (int i = 0; i < b; ++i) s += bsum[i];
        add_s = s;
    }
    __syncthreads();
    int add = add_s;
    int base = b * 1024 + t * 4;
    if (base + 3 < n) {
        int4 q = *(const int4*)(out + base);
        q.x += add; q.y += add; q.z += add; q.w += add;
        *(int4*)(out + base) = q;
    } else {
        for (int j = 0; j < 4; ++j)
            if (base + j < n) out[base + j] += add;
    }
}

// ---- p3 (+goff): partition edges into bucket-major pairs; LDS cursors only.
// blocks 0..PB-1: partition; blocks PB..PB+1: goff binary search (batch sorted).
__global__ void k_p3g(const int* __restrict__ ei, const int* __restrict__ baseG,
                      uint64* __restrict__ ebuf,
                      const int* __restrict__ batch, int* __restrict__ goff) {
    __shared__ int cur[NB2];
    int t = threadIdx.x, blk = blockIdx.x;
    if (blk >= PB) {
        int g = (blk - PB) * 512 + t;
        if (g <= NUM_GRAPHS) {
            int lo = 0, hi = N_NODES;
            while (lo < hi) {
                int mid = (lo + hi) >> 1;
                if (batch[mid] < g) lo = mid + 1; else hi = mid;
            }
            goff[g] = lo;
        }
        return;
    }
    for (int i = t; i < NB2; i += 512) cur[i] = baseG[i * PB + blk];
    __syncthreads();
    int base = blk * CHUNK;
    for (int i = t; i < CHUNK; i += 512) {
        int e = base + i;
        int src = ei[e];
        int dst = ei[N_EDGES + e];
        int pos = atomicAdd(&cur[dst >> BKT_SHIFT], 1);
        ebuf[pos] = ((uint64)(uint32)dst << 32) | (uint32)src;
    }
}

// ---- p4: one block per bucket — LDS degree count + scan, write off slice + csr ----
__global__ void k_p4(const uint64* __restrict__ ebuf, const int* __restrict__ baseG,
                     int* __restrict__ off, int* __restrict__ csr) {
    __shared__ int ldeg[512];
    __shared__ int lscan[512];
    __shared__ int lcur[512];
    int b = blockIdx.x, t = threadIdx.x;      // 512 threads
    int node0 = b << BKT_SHIFT;
    int nn = min(512, N_NODES - node0);
    int e0 = baseG[b * PB];
    int e1 = (b == NB2 - 1) ? N_EDGES : baseG[(b + 1) * PB];
    ldeg[t] = 0;
    __syncthreads();
    for (int e = e0 + t; e < e1; e += 512) {
        int dst = (int)(ebuf[e] >> 32);
        atomicAdd(&ldeg[dst - node0], 1);
    }
    __syncthreads();
    lscan[t] = ldeg[t];
    __syncthreads();
    for (int o = 1; o < 512; o <<= 1) {
        int v = (t >= o) ? lscan[t - o] : 0;
        __syncthreads();
        lscan[t] += v;
        __syncthreads();
    }
    int excl = (t == 0) ? 0 : lscan[t - 1];
    lcur[t] = e0 + excl;
    if (t < nn) off[node0 + t] = e0 + excl;
    if (b == NB2 - 1 && t == 0) off[N_NODES] = N_EDGES;
    __syncthreads();
    for (int e = e0 + t; e < e1; e += 512) {
        uint64 pr = ebuf[e];
        int dst = (int)(pr >> 32);
        int pos = atomicAdd(&lcur[dst - node0], 1);
        csr[pos] = (int)(pr & 0xffffffffu);
    }
}

// ---- aggregation (best known, R9): one wave per node, 4 lane-groups, 4-deep ----
__global__ void k_agg(const unsigned short* __restrict__ h,
                      const int* __restrict__ off, const int* __restrict__ csr,
                      unsigned short* __restrict__ hs) {
    int wid = (blockIdx.x * 256 + threadIdx.x) >> 6;
    int lane = threadIdx.x & 63;
    if (wid >= N_NODES) return;
    int g = lane >> 4, sub = lane & 15;      // group 0..3, 16B chunk 0..15
    int e0 = off[wid], e1 = off[wid + 1];
    float a[8] = {0.f, 0.f, 0.f, 0.f, 0.f, 0.f, 0.f, 0.f};
    int e = e0 + g;
    for (; e + 12 < e1; e += 16) {           // 4 edges per group in flight
        int s0 = csr[e], s1 = csr[e + 4], s2 = csr[e + 8], s3 = csr[e + 12];
        int4 v0 = *(const int4*)(h + (size_t)s0 * 128 + sub * 8);
        int4 v1 = *(const int4*)(h + (size_t)s1 * 128 + sub * 8);
        int4 v2 = *(const int4*)(h + (size_t)s2 * 128 + sub * 8);
        int4 v3 = *(const int4*)(h + (size_t)s3 * 128 + sub * 8);
        acc8(a, v0); acc8(a, v1); acc8(a, v2); acc8(a, v3);
    }
    for (; e + 4 < e1; e += 8) {             // 2 in flight
        int s0 = csr[e];
        int s1 = csr[e + 4];
        int4 v0 = *(const int4*)(h + (size_t)s0 * 128 + sub * 8);
        int4 v1 = *(const int4*)(h + (size_t)s1 * 128 + sub * 8);
        acc8(a, v0);
        acc8(a, v1);
    }
    if (e < e1) {
        int s0 = csr[e];
        int4 v0 = *(const int4*)(h + (size_t)s0 * 128 + sub * 8);
        acc8(a, v0);
    }
    // combine the 4 group-partials (lanes sub, sub+16, sub+32, sub+48)
#pragma unroll
    for (int j = 0; j < 8; ++j) {
        a[j] += __shfl_xor(a[j], 16);
        a[j] += __shfl_xor(a[j], 32);
    }
    if (g == 0) {
        int4 sv = *(const int4*)(h + (size_t)wid * 128 + sub * 8);
        acc8(a, sv);                          // + self
        int4 o;
        o.x = (int)((uint32)f2b(a[0]) | ((uint32)f2b(a[1]) << 16));
        o.y = (int)((uint32)f2b(a[2]) | ((uint32)f2b(a[3]) << 16));
        o.z = (int)((uint32)f2b(a[4]) | ((uint32)f2b(a[5]) << 16));
        o.w = (int)((uint32)f2b(a[6]) | ((uint32)f2b(a[7]) << 16));
        *(int4*)(hs + (size_t)wid * 128 + sub * 8) = o;
    }
}

// ---- fused 2-layer MLP v2: 64-row blocks; A-tile staged to LDS ONCE (coalesced),
// mm1 in-place band-by-band from LDS (no 4x redundant global A reads), mm2 in-place,
// coalesced copy-out. 4 waves x 32-col slices, weights in regs.
template<int OUTER_RELU>
__global__ void k_mlp(const unsigned short* __restrict__ hs,
                      const unsigned short* __restrict__ w1t, const float* __restrict__ b1,
                      const unsigned short* __restrict__ w2t, const float* __restrict__ b2,
                      unsigned short* __restrict__ ho) {
    __shared__ unsigned short T[64 * 128];   // 16 KB, XOR-swizzled ((r&7)<<4 on byte addr)
    int tid = threadIdx.x;
    int lane = tid & 63, wave = tid >> 6;
    int l15 = lane & 15, l4 = lane >> 4;
    int row0 = blockIdx.x * 64;
    int wn0 = wave * 32;                      // this wave's output-col base

    // ---- stage-in: A tile (64x128 bf16) coalesced -> swizzled LDS, 4 chunks/thread ----
    for (int c = tid; c < 1024; c += 256) {
        int r = c >> 4, cc = c & 15;
        int gr = row0 + r;
        if (gr >= N_NODES) gr = N_NODES - 1;          // tail clamp (rows never copied out)
        int4 v = *(const int4*)(hs + (size_t)gr * 128 + cc * 8);
        int byte = (r * 256 + cc * 16) ^ ((r & 7) << 4);
        *(int4*)((char*)T + byte) = v;
    }

    bf16x8 w1f[2][4], w2f[2][4];
#pragma unroll
    for (int nt = 0; nt < 2; ++nt)
#pragma unroll
        for (int k = 0; k < 4; ++k) {
            int o = (wn0 + nt * 16 + l15) * 128 + k * 32 + l4 * 8;
            w1f[nt][k] = *(const bf16x8*)(w1t + o);
            w2f[nt][k] = *(const bf16x8*)(w2t + o);
        }
    float bias1[2] = { b1[wn0 + l15], b1[wn0 + 16 + l15] };
    float bias2[2] = { b2[wn0 + l15], b2[wn0 + 16 + l15] };
    __syncthreads();

    // ---- mm1: band-by-band in place (read A band -> barrier -> write relu(A@W1+b1)) ----
#pragma unroll
    for (int mt = 0; mt < 4; ++mt) {
        int trow = mt * 16 + l15;
        int sw = (trow & 7) << 4;
        int rb = trow * 256 + l4 * 16;
        bf16x8 a0 = *(const bf16x8*)((const char*)T + ((rb + 0)   ^ sw));
        bf16x8 a1 = *(const bf16x8*)((const char*)T + ((rb + 64)  ^ sw));
        bf16x8 a2 = *(const bf16x8*)((const char*)T + ((rb + 128) ^ sw));
        bf16x8 a3 = *(const bf16x8*)((const char*)T + ((rb + 192) ^ sw));
        __syncthreads();   // all waves done reading band mt before anyone overwrites it
#pragma unroll
        for (int nt = 0; nt < 2; ++nt) {
            f32x4 acc = {0.f, 0.f, 0.f, 0.f};
            acc = __builtin_amdgcn_mfma_f32_16x16x32_bf16(a0, w1f[nt][0], acc, 0, 0, 0);
            acc = __builtin_amdgcn_mfma_f32_16x16x32_bf16(a1, w1f[nt][1], acc, 0, 0, 0);
            acc = __builtin_amdgcn_mfma_f32_16x16x32_bf16(a2, w1f[nt][2], acc, 0, 0, 0);
            acc = __builtin_amdgcn_mfma_f32_16x16x32_bf16(a3, w1f[nt][3], acc, 0, 0, 0);
#pragma unroll
            for (int j = 0; j < 4; ++j) {
                float v = fmaxf(acc[j] + bias1[nt], 0.f);
                int orow = mt * 16 + l4 * 4 + j;
                int ocol = wn0 + nt * 16 + l15;
                int byte = (orow * 256 + ocol * 2) ^ ((orow & 7) << 4);
                *(unsigned short*)((char*)T + byte) = f2b(v);
            }
        }
    }
    __syncthreads();

    // ---- mm2: band-by-band, outputs written back into T in place ----
#pragma unroll
    for (int mt = 0; mt < 4; ++mt) {
        int trow = mt * 16 + l15;
        int sw = (trow & 7) << 4;
        int rb = trow * 256 + l4 * 16;
        bf16x8 t0 = *(const bf16x8*)((const char*)T + ((rb + 0)   ^ sw));
        bf16x8 t1 = *(const bf16x8*)((const char*)T + ((rb + 64)  ^ sw));
        bf16x8 t2 = *(const bf16x8*)((const char*)T + ((rb + 128) ^ sw));
        bf16x8 t3 = *(const bf16x8*)((const char*)T + ((rb + 192) ^ sw));
        __syncthreads();
#pragma unroll
        for (int nt = 0; nt < 2; ++nt) {
            f32x4 acc = {0.f, 0.f, 0.f, 0.f};
            acc = __builtin_amdgcn_mfma_f32_16x16x32_bf16(t0, w2f[nt][0], acc, 0, 0, 0);
            acc = __builtin_amdgcn_mfma_f32_16x16x32_bf16(t1, w2f[nt][1], acc, 0, 0, 0);
            acc = __builtin_amdgcn_mfma_f32_16x16x32_bf16(t2, w2f[nt][2], acc, 0, 0, 0);
            acc = __builtin_amdgcn_mfma_f32_16x16x32_bf16(t3, w2f[nt][3], acc, 0, 0, 0);
#pragma unroll
            for (int j = 0; j < 4; ++j) {
                float v = acc[j] + bias2[nt];
                if (OUTER_RELU) v = fmaxf(v, 0.f);
                int orow = mt * 16 + l4 * 4 + j;
                int ocol = wn0 + nt * 16 + l15;
                int byte = (orow * 256 + ocol * 2) ^ ((orow & 7) << 4);
                *(unsigned short*)((char*)T + byte) = f2b(v);
            }
        }
    }
    __syncthreads();

    // ---- coalesced copy-out: 1024 16B chunks, 4 per thread ----
    for (int c = tid; c < 1024; c += 256) {
        int r = c >> 4, cc = c & 15;
        int byte = (r * 256 + cc * 16) ^ ((r & 7) << 4);
        int4 v = *(const int4*)((const char*)T + byte);
        int gr = row0 + r;
        if (gr < N_NODES)
            *(int4*)(ho + (size_t)gr * 128 + cc * 8) = v;
    }
}

// ---- per-graph mean pool + final linear: 4 waves per graph, LDS combine ----
__global__ void k_pool(const unsigned short* __restrict__ h,
                       const int* __restrict__ goff,
                       const float* __restrict__ wl, const float* __restrict__ bl,
                       float* __restrict__ out) {
    __shared__ float sm[4][64][2];
    int g = blockIdx.x;
    int tid = threadIdx.x;                 // 256 threads
    int wave = tid >> 6, lane = tid & 63;
    int e0 = goff[g], e1 = goff[g + 1];
    int c2 = lane << 1;
    float s0 = 0.f, s1 = 0.f;
    int r = e0 + wave;
    // 2 rows in flight per lane (rows r, r+4), stride 8
    for (; r + 4 < e1; r += 8) {
        uint32 v0 = *(const uint32*)(h + (size_t)r * 128 + c2);
        uint32 v1 = *(const uint32*)(h + (size_t)(r + 4) * 128 + c2);
        s0 += b2f(v0 & 0xffffu) + b2f(v1 & 0xffffu);
        s1 += b2f(v0 >> 16) + b2f(v1 >> 16);
    }
    if (r < e1) {
        uint32 v = *(const uint32*)(h + (size_t)r * 128 + c2);
        s0 += b2f(v & 0xffffu);
        s1 += b2f(v >> 16);
    }
    sm[wave][lane][0] = s0;
    sm[wave][lane][1] = s1;
    __syncthreads();
    if (wave == 0) {
        s0 = sm[0][lane][0] + sm[1][lane][0] + sm[2][lane][0] + sm[3][lane][0];
        s1 = sm[0][lane][1] + sm[1][lane][1] + sm[2][lane][1] + sm[3][lane][1];
        float inv = 1.f / fmaxf((float)(e1 - e0), 1.f);
        s0 *= inv; s1 *= inv;
        float o0 = s0 * wl[c2 * 2]     + s1 * wl[(c2 + 1) * 2];
        float o1 = s0 * wl[c2 * 2 + 1] + s1 * wl[(c2 + 1) * 2 + 1];
#pragma unroll
        for (int d = 32; d; d >>= 1) {
            o0 += __shfl_down(o0, d);
            o1 += __shfl_down(o1, d);
        }
        if (lane == 0) {
            out[g * 2]     = o0 + bl[0];
            out[g * 2 + 1] = o1 + bl[1];
        }
    }
}

extern "C" void kernel_launch(void* const* d_in, const int* in_sizes, int n_in,
                              void* d_out, int out_size, void* d_ws, size_t ws_size,
                              hipStream_t stream) {
    const float* x     = (const float*)d_in[0];
    const int*   ei    = (const int*)d_in[1];
    const int*   batch = (const int*)d_in[2];
    const float* w1[3] = {(const float*)d_in[3],  (const float*)d_in[7],  (const float*)d_in[11]};
    const float* b1[3] = {(const float*)d_in[4],  (const float*)d_in[8],  (const float*)d_in[12]};
    const float* w2[3] = {(const float*)d_in[5],  (const float*)d_in[9],  (const float*)d_in[13]};
    const float* b2[3] = {(const float*)d_in[6],  (const float*)d_in[10], (const float*)d_in[14]};
    const float* wl    = (const float*)d_in[15];
    const float* bl    = (const float*)d_in[16];

    char* p = (char*)d_ws;
    auto alloc = [&](size_t bytes) {
        char* r = p;
        p += (bytes + 255) & ~(size_t)255;
        return r;
    };
    int* off    = (int*)alloc((size_t)(N_NODES + 1) * 4);
    int* goff   = (int*)alloc((size_t)(NUM_GRAPHS + 1) * 4);
    int* histG  = (int*)alloc((size_t)(NB2 * PB) * 4);
    int* baseG  = (int*)alloc((size_t)(NB2 * PB + 1) * 4);
    int* bsum   = (int*)alloc((size_t)128 * 4);
    int* csr    = (int*)alloc((size_t)N_EDGES * 4);
    unsigned short* wts = (unsigned short*)alloc((size_t)6 * 16384 * 2);
    unsigned short* hA  = (unsigned short*)alloc((size_t)N_NODES * 128 * 2);
    unsigned short* hS  = (unsigned short*)alloc((size_t)N_NODES * 128 * 2);
    unsigned short* hB  = (unsigned short*)alloc((size_t)N_NODES * 128 * 2);
    uint64* ebuf = (uint64*)hS;   // alias: hS first written after CSR build completes

    // ---- merged front: cast | wprep | p1 histogram ----
    k_front<<<NCAST + 6 + PB, 256, 0, stream>>>(x, hA,
        w1[0], w2[0], w1[1], w2[1], w1[2], w2[2], wts, ei + N_EDGES, histG);

    // ---- CSR build: block-binned counting sort, zero global atomics ----
    const int SCAN_N = NB2 * PB;                        // 39200
    const int SCAN_BLOCKS = (SCAN_N + 1023) / 1024;     // 39
    k_scan1<<<SCAN_BLOCKS, 256, 0, stream>>>(histG, baseG, bsum, SCAN_N);
    k_scan3b<<<SCAN_BLOCKS, 256, 0, stream>>>(baseG, bsum, SCAN_N);
    k_p3g<<<PB + 2, 512, 0, stream>>>(ei, baseG, ebuf, batch, goff);
    k_p4<<<NB2, 512, 0, stream>>>(ebuf, baseG, off, csr);

    unsigned short* wt1[3] = {wts,             wts + 2 * 16384, wts + 4 * 16384};
    unsigned short* wt2[3] = {wts + 1 * 16384, wts + 3 * 16384, wts + 5 * 16384};

    const int AGG_GRID = N_NODES / 4;                   // one wave per node: 25000 blocks
    const int MLP_GRID = (N_NODES + 63) / 64;           // 1563 blocks, 64 rows each

    // layer 0
    k_agg<<<AGG_GRID, 256, 0, stream>>>(hA, off, csr, hS);
    k_mlp<1><<<MLP_GRID, 256, 0, stream>>>(hS, wt1[0], b1[0], wt2[0], b2[0], hB);
    // layer 1
    k_agg<<<AGG_GRID, 256, 0, stream>>>(hB, off, csr, hS);
    k_mlp<1><<<MLP_GRID, 256, 0, stream>>>(hS, wt1[1], b1[1], wt2[1], b2[1], hA);
    // layer 2 (no outer relu)
    k_agg<<<AGG_GRID, 256, 0, stream>>>(hA, off, csr, hS);
    k_mlp<0><<<MLP_GRID, 256, 0, stream>>>(hS, wt1[2], b1[2], wt2[2], b2[2], hB);

    k_pool<<<NUM_GRAPHS, 256, 0, stream>>>(hB, goff, wl, bl, (float*)d_out);
}

// Round 16
// 325.265 us; speedup vs baseline: 1.2128x; 1.0082x over previous
//
#include <hip/hip_runtime.h>
#include <hip/hip_bf16.h>

#define N_NODES   100000
#define N_EDGES   1600000
#define IN_CH     128
#define HID       128
#define OUT_CH    2
#define NUM_GRAPHS 512

// counting-sort geometry: 512 nodes per bucket, 200 partition blocks x 8000 edges
#define BKT_SHIFT 9
#define NB2 ((N_NODES + 511) >> BKT_SHIFT)   // 196 buckets
#define PB  200                               // partition blocks
#define CHUNK (N_EDGES / PB)                  // 8000 edges per block (exact)

#define NCAST (N_NODES * IN_CH / 4 / 256)     // 12500 cast blocks

typedef __attribute__((ext_vector_type(8))) short bf16x8;
typedef __attribute__((ext_vector_type(4))) float f32x4;
typedef unsigned int uint32;
typedef unsigned long long uint64;

static __device__ __forceinline__ float b2f(uint32 b) {
    return __uint_as_float(b << 16);
}
static __device__ __forceinline__ unsigned short f2b(float f) {
    uint32 u = __float_as_uint(f);
    u += 0x7fffu + ((u >> 16) & 1u);   // round-to-nearest-even
    return (unsigned short)(u >> 16);
}
static __device__ __forceinline__ void acc8(float* a, int4 v) {
    uint32 x;
    x = (uint32)v.x; a[0] += __uint_as_float(x << 16); a[1] += __uint_as_float(x & 0xffff0000u);
    x = (uint32)v.y; a[2] += __uint_as_float(x << 16); a[3] += __uint_as_float(x & 0xffff0000u);
    x = (uint32)v.z; a[4] += __uint_as_float(x << 16); a[5] += __uint_as_float(x & 0xffff0000u);
    x = (uint32)v.w; a[6] += __uint_as_float(x << 16); a[7] += __uint_as_float(x & 0xffff0000u);
}

// ---- merged front kernel: cast | weight-prep | bucket histogram ----
__global__ void k_front(const float* __restrict__ x, unsigned short* __restrict__ h,
                        const float* w0, const float* w1, const float* w2,
                        const float* w3, const float* w4, const float* w5,
                        unsigned short* __restrict__ wt,
                        const int* __restrict__ dst, int* __restrict__ histG) {
    __shared__ int hist[NB2];
    int bid = blockIdx.x, t = threadIdx.x;
    if (bid < NCAST) {
        // cast x (f32) -> bf16, 4 elems/thread
        int base = (bid * 256 + t) * 4;
        float4 v = *(const float4*)(x + base);
        ushort4 o;
        o.x = f2b(v.x); o.y = f2b(v.y); o.z = f2b(v.z); o.w = f2b(v.w);
        *(ushort4*)(h + base) = o;
    } else if (bid < NCAST + 6) {
        // transpose + cast one 128x128 weight matrix
        const float* ws[6] = {w0, w1, w2, w3, w4, w5};
        int wi = bid - NCAST;
        const float* w = ws[wi];
        unsigned short* o = wt + wi * 16384;
        for (int i = t; i < 16384; i += 256) {
            int k = i >> 7, n = i & 127;
            o[n * 128 + k] = f2b(w[i]);
        }
    } else {
        // per-block LDS bucket histogram (no global atomics)
        int blk = bid - NCAST - 6;
        for (int i = t; i < NB2; i += 256) hist[i] = 0;
        __syncthreads();
        int base = blk * CHUNK;
        for (int i = t; i < CHUNK; i += 256)
            atomicAdd(&hist[dst[base + i] >> BKT_SHIFT], 1);
        __syncthreads();
        for (int i = t; i < NB2; i += 256) histG[i * PB + blk] = hist[i];
    }
}

// ---- two-level scan: stage 1 — per-block (1024 elems) local exclusive scan ----
__global__ void k_scan1(const int* __restrict__ in, int* __restrict__ out,
                        int* __restrict__ bsum, int n) {
    __shared__ int sm[256];
    int b = blockIdx.x, t = threadIdx.x;
    int base = b * 1024 + t * 4;
    int v0 = 0, v1 = 0, v2 = 0, v3 = 0;
    if (base + 3 < n) {
        int4 q = *(const int4*)(in + base);
        v0 = q.x; v1 = q.y; v2 = q.z; v3 = q.w;
    } else {
        if (base + 0 < n) v0 = in[base + 0];
        if (base + 1 < n) v1 = in[base + 1];
        if (base + 2 < n) v2 = in[base + 2];
        if (base + 3 < n) v3 = in[base + 3];
    }
    int s = v0 + v1 + v2 + v3;
    sm[t] = s;
    __syncthreads();
    for (int off = 1; off < 256; off <<= 1) {
        int u = (t >= off) ? sm[t - off] : 0;
        __syncthreads();
        sm[t] += u;
        __syncthreads();
    }
    int p = (t == 0) ? 0 : sm[t - 1];
    int o0 = p, o1 = p + v0, o2 = o1 + v1, o3 = o2 + v2;
    if (base + 3 < n) {
        *(int4*)(out + base) = make_int4(o0, o1, o2, o3);
    } else {
        if (base + 0 < n) out[base + 0] = o0;
        if (base + 1 < n) out[base + 1] = o1;
        if (base + 2 < n) out[base + 2] = o2;
        if (base + 3 < n) out[base + 3] = o3;
    }
    if (t == 255) bsum[b] = s + ((t == 0) ? 0 : sm[t - 1]);
}

// ---- stage 2+3 merged: each block locally prefixes bsum, adds in place ----
__global__ void k_scan3b(int* __restrict__ out, const int* __restrict__ bsum, int n) {
    __shared__ int add_s;
    int b = blockIdx.x, t = threadIdx.x;
    if (t == 0) {
        int s = 0;
        for (int i = 0; i < b; ++i) s += bsum[i];
        add_s = s;
    }
    __syncthreads();
    int add = add_s;
    int base = b * 1024 + t * 4;
    if (base + 3 < n) {
        int4 q = *(const int4*)(out + base);
        q.x += add; q.y += add; q.z += add; q.w += add;
        *(int4*)(out + base) = q;
    } else {
        for (int j = 0; j < 4; ++j)
            if (base + j < n) out[base + j] += add;
    }
}

// ---- p3 (+goff): partition edges into bucket-major pairs; LDS cursors only.
// blocks 0..PB-1: partition; blocks PB..PB+1: goff binary search (batch sorted).
__global__ void k_p3g(const int* __restrict__ ei, const int* __restrict__ baseG,
                      uint64* __restrict__ ebuf,
                      const int* __restrict__ batch, int* __restrict__ goff) {
    __shared__ int cur[NB2];
    int t = threadIdx.x, blk = blockIdx.x;
    if (blk >= PB) {
        int g = (blk - PB) * 512 + t;
        if (g <= NUM_GRAPHS) {
            int lo = 0, hi = N_NODES;
            while (lo < hi) {
                int mid = (lo + hi) >> 1;
                if (batch[mid] < g) lo = mid + 1; else hi = mid;
            }
            goff[g] = lo;
        }
        return;
    }
    for (int i = t; i < NB2; i += 512) cur[i] = baseG[i * PB + blk];
    __syncthreads();
    int base = blk * CHUNK;
    for (int i = t; i < CHUNK; i += 512) {
        int e = base + i;
        int src = ei[e];
        int dst = ei[N_EDGES + e];
        int pos = atomicAdd(&cur[dst >> BKT_SHIFT], 1);
        ebuf[pos] = ((uint64)(uint32)dst << 32) | (uint32)src;
    }
}

// ---- p4: one block per bucket — LDS degree count + scan, write off slice + csr ----
__global__ void k_p4(const uint64* __restrict__ ebuf, const int* __restrict__ baseG,
                     int* __restrict__ off, int* __restrict__ csr) {
    __shared__ int ldeg[512];
    __shared__ int lscan[512];
    __shared__ int lcur[512];
    int b = blockIdx.x, t = threadIdx.x;      // 512 threads
    int node0 = b << BKT_SHIFT;
    int nn = min(512, N_NODES - node0);
    int e0 = baseG[b * PB];
    int e1 = (b == NB2 - 1) ? N_EDGES : baseG[(b + 1) * PB];
    ldeg[t] = 0;
    __syncthreads();
    for (int e = e0 + t; e < e1; e += 512) {
        int dst = (int)(ebuf[e] >> 32);
        atomicAdd(&ldeg[dst - node0], 1);
    }
    __syncthreads();
    lscan[t] = ldeg[t];
    __syncthreads();
    for (int o = 1; o < 512; o <<= 1) {
        int v = (t >= o) ? lscan[t - o] : 0;
        __syncthreads();
        lscan[t] += v;
        __syncthreads();
    }
    int excl = (t == 0) ? 0 : lscan[t - 1];
    lcur[t] = e0 + excl;
    if (t < nn) off[node0 + t] = e0 + excl;
    if (b == NB2 - 1 && t == 0) off[N_NODES] = N_EDGES;
    __syncthreads();
    for (int e = e0 + t; e < e1; e += 512) {
        uint64 pr = ebuf[e];
        int dst = (int)(pr >> 32);
        int pos = atomicAdd(&lcur[dst - node0], 1);
        csr[pos] = (int)(pr & 0xffffffffu);
    }
}

// ---- aggregation (best known, R9): one wave per node, 4 lane-groups, 4-deep ----
__global__ void k_agg(const unsigned short* __restrict__ h,
                      const int* __restrict__ off, const int* __restrict__ csr,
                      unsigned short* __restrict__ hs) {
    int wid = (blockIdx.x * 256 + threadIdx.x) >> 6;
    int lane = threadIdx.x & 63;
    if (wid >= N_NODES) return;
    int g = lane >> 4, sub = lane & 15;      // group 0..3, 16B chunk 0..15
    int e0 = off[wid], e1 = off[wid + 1];
    float a[8] = {0.f, 0.f, 0.f, 0.f, 0.f, 0.f, 0.f, 0.f};
    int e = e0 + g;
    for (; e + 12 < e1; e += 16) {           // 4 edges per group in flight
        int s0 = csr[e], s1 = csr[e + 4], s2 = csr[e + 8], s3 = csr[e + 12];
        int4 v0 = *(const int4*)(h + (size_t)s0 * 128 + sub * 8);
        int4 v1 = *(const int4*)(h + (size_t)s1 * 128 + sub * 8);
        int4 v2 = *(const int4*)(h + (size_t)s2 * 128 + sub * 8);
        int4 v3 = *(const int4*)(h + (size_t)s3 * 128 + sub * 8);
        acc8(a, v0); acc8(a, v1); acc8(a, v2); acc8(a, v3);
    }
    for (; e + 4 < e1; e += 8) {             // 2 in flight
        int s0 = csr[e];
        int s1 = csr[e + 4];
        int4 v0 = *(const int4*)(h + (size_t)s0 * 128 + sub * 8);
        int4 v1 = *(const int4*)(h + (size_t)s1 * 128 + sub * 8);
        acc8(a, v0);
        acc8(a, v1);
    }
    if (e < e1) {
        int s0 = csr[e];
        int4 v0 = *(const int4*)(h + (size_t)s0 * 128 + sub * 8);
        acc8(a, v0);
    }
    // combine the 4 group-partials (lanes sub, sub+16, sub+32, sub+48)
#pragma unroll
    for (int j = 0; j < 8; ++j) {
        a[j] += __shfl_xor(a[j], 16);
        a[j] += __shfl_xor(a[j], 32);
    }
    if (g == 0) {
        int4 sv = *(const int4*)(h + (size_t)wid * 128 + sub * 8);
        acc8(a, sv);                          // + self
        int4 o;
        o.x = (int)((uint32)f2b(a[0]) | ((uint32)f2b(a[1]) << 16));
        o.y = (int)((uint32)f2b(a[2]) | ((uint32)f2b(a[3]) << 16));
        o.z = (int)((uint32)f2b(a[4]) | ((uint32)f2b(a[5]) << 16));
        o.w = (int)((uint32)f2b(a[6]) | ((uint32)f2b(a[7]) << 16));
        *(int4*)(hs + (size_t)wid * 128 + sub * 8) = o;
    }
}

// ---- fused 2-layer MLP (layers 0/1): 64-row blocks; A staged to LDS once,
// mm1 in-place, mm2 in-place, coalesced copy-out. 4 waves x 32-col, weights in regs.
template<int OUTER_RELU>
__global__ void k_mlp(const unsigned short* __restrict__ hs,
                      const unsigned short* __restrict__ w1t, const float* __restrict__ b1,
                      const unsigned short* __restrict__ w2t, const float* __restrict__ b2,
                      unsigned short* __restrict__ ho) {
    __shared__ unsigned short T[64 * 128];   // 16 KB, XOR-swizzled ((r&7)<<4 on byte addr)
    int tid = threadIdx.x;
    int lane = tid & 63, wave = tid >> 6;
    int l15 = lane & 15, l4 = lane >> 4;
    int row0 = blockIdx.x * 64;
    int wn0 = wave * 32;                      // this wave's output-col base

    // ---- stage-in: A tile (64x128 bf16) coalesced -> swizzled LDS, 4 chunks/thread ----
    for (int c = tid; c < 1024; c += 256) {
        int r = c >> 4, cc = c & 15;
        int gr = row0 + r;
        if (gr >= N_NODES) gr = N_NODES - 1;          // tail clamp (rows never copied out)
        int4 v = *(const int4*)(hs + (size_t)gr * 128 + cc * 8);
        int byte = (r * 256 + cc * 16) ^ ((r & 7) << 4);
        *(int4*)((char*)T + byte) = v;
    }

    bf16x8 w1f[2][4], w2f[2][4];
#pragma unroll
    for (int nt = 0; nt < 2; ++nt)
#pragma unroll
        for (int k = 0; k < 4; ++k) {
            int o = (wn0 + nt * 16 + l15) * 128 + k * 32 + l4 * 8;
            w1f[nt][k] = *(const bf16x8*)(w1t + o);
            w2f[nt][k] = *(const bf16x8*)(w2t + o);
        }
    float bias1[2] = { b1[wn0 + l15], b1[wn0 + 16 + l15] };
    float bias2[2] = { b2[wn0 + l15], b2[wn0 + 16 + l15] };
    __syncthreads();

    // ---- mm1: band-by-band in place ----
#pragma unroll
    for (int mt = 0; mt < 4; ++mt) {
        int trow = mt * 16 + l15;
        int sw = (trow & 7) << 4;
        int rb = trow * 256 + l4 * 16;
        bf16x8 a0 = *(const bf16x8*)((const char*)T + ((rb + 0)   ^ sw));
        bf16x8 a1 = *(const bf16x8*)((const char*)T + ((rb + 64)  ^ sw));
        bf16x8 a2 = *(const bf16x8*)((const char*)T + ((rb + 128) ^ sw));
        bf16x8 a3 = *(const bf16x8*)((const char*)T + ((rb + 192) ^ sw));
        __syncthreads();
#pragma unroll
        for (int nt = 0; nt < 2; ++nt) {
            f32x4 acc = {0.f, 0.f, 0.f, 0.f};
            acc = __builtin_amdgcn_mfma_f32_16x16x32_bf16(a0, w1f[nt][0], acc, 0, 0, 0);
            acc = __builtin_amdgcn_mfma_f32_16x16x32_bf16(a1, w1f[nt][1], acc, 0, 0, 0);
            acc = __builtin_amdgcn_mfma_f32_16x16x32_bf16(a2, w1f[nt][2], acc, 0, 0, 0);
            acc = __builtin_amdgcn_mfma_f32_16x16x32_bf16(a3, w1f[nt][3], acc, 0, 0, 0);
#pragma unroll
            for (int j = 0; j < 4; ++j) {
                float v = fmaxf(acc[j] + bias1[nt], 0.f);
                int orow = mt * 16 + l4 * 4 + j;
                int ocol = wn0 + nt * 16 + l15;
                int byte = (orow * 256 + ocol * 2) ^ ((orow & 7) << 4);
                *(unsigned short*)((char*)T + byte) = f2b(v);
            }
        }
    }
    __syncthreads();

    // ---- mm2: band-by-band in place ----
#pragma unroll
    for (int mt = 0; mt < 4; ++mt) {
        int trow = mt * 16 + l15;
        int sw = (trow & 7) << 4;
        int rb = trow * 256 + l4 * 16;
        bf16x8 t0 = *(const bf16x8*)((const char*)T + ((rb + 0)   ^ sw));
        bf16x8 t1 = *(const bf16x8*)((const char*)T + ((rb + 64)  ^ sw));
        bf16x8 t2 = *(const bf16x8*)((const char*)T + ((rb + 128) ^ sw));
        bf16x8 t3 = *(const bf16x8*)((const char*)T + ((rb + 192) ^ sw));
        __syncthreads();
#pragma unroll
        for (int nt = 0; nt < 2; ++nt) {
            f32x4 acc = {0.f, 0.f, 0.f, 0.f};
            acc = __builtin_amdgcn_mfma_f32_16x16x32_bf16(t0, w2f[nt][0], acc, 0, 0, 0);
            acc = __builtin_amdgcn_mfma_f32_16x16x32_bf16(t1, w2f[nt][1], acc, 0, 0, 0);
            acc = __builtin_amdgcn_mfma_f32_16x16x32_bf16(t2, w2f[nt][2], acc, 0, 0, 0);
            acc = __builtin_amdgcn_mfma_f32_16x16x32_bf16(t3, w2f[nt][3], acc, 0, 0, 0);
#pragma unroll
            for (int j = 0; j < 4; ++j) {
                float v = acc[j] + bias2[nt];
                if (OUTER_RELU) v = fmaxf(v, 0.f);
                int orow = mt * 16 + l4 * 4 + j;
                int ocol = wn0 + nt * 16 + l15;
                int byte = (orow * 256 + ocol * 2) ^ ((orow & 7) << 4);
                *(unsigned short*)((char*)T + byte) = f2b(v);
            }
        }
    }
    __syncthreads();

    // ---- coalesced copy-out: 1024 16B chunks, 4 per thread ----
    for (int c = tid; c < 1024; c += 256) {
        int r = c >> 4, cc = c & 15;
        int byte = (r * 256 + cc * 16) ^ ((r & 7) << 4);
        int4 v = *(const int4*)((const char*)T + byte);
        int gr = row0 + r;
        if (gr < N_NODES)
            *(int4*)(ho + (size_t)gr * 128 + cc * 8) = v;
    }
}

// ---- layer 2: mm1 then per-graph column-sum of T (pool pushed before linear mm2).
// batch sorted -> per-thread running sum, flush on graph change (few atomics).
__global__ void k_mlp2(const unsigned short* __restrict__ hs,
                       const unsigned short* __restrict__ w1t, const float* __restrict__ b1,
                       const int* __restrict__ batch, float* __restrict__ gsum) {
    __shared__ unsigned short T[64 * 128];
    int tid = threadIdx.x;
    int lane = tid & 63, wave = tid >> 6;
    int l15 = lane & 15, l4 = lane >> 4;
    int row0 = blockIdx.x * 64;
    int wn0 = wave * 32;

    for (int c = tid; c < 1024; c += 256) {
        int r = c >> 4, cc = c & 15;
        int gr = row0 + r;
        if (gr >= N_NODES) gr = N_NODES - 1;
        int4 v = *(const int4*)(hs + (size_t)gr * 128 + cc * 8);
        int byte = (r * 256 + cc * 16) ^ ((r & 7) << 4);
        *(int4*)((char*)T + byte) = v;
    }

    bf16x8 w1f[2][4];
#pragma unroll
    for (int nt = 0; nt < 2; ++nt)
#pragma unroll
        for (int k = 0; k < 4; ++k) {
            int o = (wn0 + nt * 16 + l15) * 128 + k * 32 + l4 * 8;
            w1f[nt][k] = *(const bf16x8*)(w1t + o);
        }
    float bias1[2] = { b1[wn0 + l15], b1[wn0 + 16 + l15] };
    __syncthreads();

    // ---- mm1: band-by-band in place ----
#pragma unroll
    for (int mt = 0; mt < 4; ++mt) {
        int trow = mt * 16 + l15;
        int sw = (trow & 7) << 4;
        int rb = trow * 256 + l4 * 16;
        bf16x8 a0 = *(const bf16x8*)((const char*)T + ((rb + 0)   ^ sw));
        bf16x8 a1 = *(const bf16x8*)((const char*)T + ((rb + 64)  ^ sw));
        bf16x8 a2 = *(const bf16x8*)((const char*)T + ((rb + 128) ^ sw));
        bf16x8 a3 = *(const bf16x8*)((const char*)T + ((rb + 192) ^ sw));
        __syncthreads();
#pragma unroll
        for (int nt = 0; nt < 2; ++nt) {
            f32x4 acc = {0.f, 0.f, 0.f, 0.f};
            acc = __builtin_amdgcn_mfma_f32_16x16x32_bf16(a0, w1f[nt][0], acc, 0, 0, 0);
            acc = __builtin_amdgcn_mfma_f32_16x16x32_bf16(a1, w1f[nt][1], acc, 0, 0, 0);
            acc = __builtin_amdgcn_mfma_f32_16x16x32_bf16(a2, w1f[nt][2], acc, 0, 0, 0);
            acc = __builtin_amdgcn_mfma_f32_16x16x32_bf16(a3, w1f[nt][3], acc, 0, 0, 0);
#pragma unroll
            for (int j = 0; j < 4; ++j) {
                float v = fmaxf(acc[j] + bias1[nt], 0.f);
                int orow = mt * 16 + l4 * 4 + j;
                int ocol = wn0 + nt * 16 + l15;
                int byte = (orow * 256 + ocol * 2) ^ ((orow & 7) << 4);
                *(unsigned short*)((char*)T + byte) = f2b(v);
            }
        }
    }
    __syncthreads();

    // ---- per-graph column sums: thread owns col (tid&127), rows half*32..+31 ----
    int col = tid & 127, half = tid >> 7;
    float acc = 0.f;
    int curg = -1;
    for (int r = half * 32; r < half * 32 + 32; ++r) {
        int gr = row0 + r;
        if (gr >= N_NODES) break;
        int g = batch[gr];
        if (g != curg) {
            if (curg >= 0) atomicAdd(&gsum[curg * 128 + col], acc);
            curg = g; acc = 0.f;
        }
        int byte = (r * 256 + col * 2) ^ ((r & 7) << 4);
        acc += b2f(*(const unsigned short*)((const char*)T + byte));
    }
    if (curg >= 0) atomicAdd(&gsum[curg * 128 + col], acc);
}

// ---- final: out[g] = ((gsum[g]/cnt)@W2 + b2) @ wl + bl — one wave per graph ----
__global__ void k_final(const float* __restrict__ gsum, const int* __restrict__ goff,
                        const unsigned short* __restrict__ w2t, const float* __restrict__ b2,
                        const float* __restrict__ wl, const float* __restrict__ bl,
                        float* __restrict__ out) {
    __shared__ float ts[128];
    int g = blockIdx.x;
    int lane = threadIdx.x;   // 64
    float inv = 1.f / fmaxf((float)(goff[g + 1] - goff[g]), 1.f);
    ts[lane * 2]     = gsum[g * 128 + lane * 2] * inv;
    ts[lane * 2 + 1] = gsum[g * 128 + lane * 2 + 1] * inv;
    __syncthreads();
    float y[2];
#pragma unroll
    for (int cc = 0; cc < 2; ++cc) {
        int col = lane * 2 + cc;
        const bf16x8* wp = (const bf16x8*)(w2t + col * 128);
        float a = 0.f;
#pragma unroll
        for (int k8 = 0; k8 < 16; ++k8) {
            bf16x8 w = wp[k8];
#pragma unroll
            for (int j = 0; j < 8; ++j)
                a += ts[k8 * 8 + j] * b2f((uint32)(unsigned short)w[j]);
        }
        y[cc] = a + b2[col];
    }
    float o0 = y[0] * wl[(lane * 2) * 2]     + y[1] * wl[(lane * 2 + 1) * 2];
    float o1 = y[0] * wl[(lane * 2) * 2 + 1] + y[1] * wl[(lane * 2 + 1) * 2 + 1];
#pragma unroll
    for (int d = 32; d; d >>= 1) {
        o0 += __shfl_down(o0, d);
        o1 += __shfl_down(o1, d);
    }
    if (lane == 0) {
        out[g * 2]     = o0 + bl[0];
        out[g * 2 + 1] = o1 + bl[1];
    }
}

extern "C" void kernel_launch(void* const* d_in, const int* in_sizes, int n_in,
                              void* d_out, int out_size, void* d_ws, size_t ws_size,
                              hipStream_t stream) {
    const float* x     = (const float*)d_in[0];
    const int*   ei    = (const int*)d_in[1];
    const int*   batch = (const int*)d_in[2];
    const float* w1[3] = {(const float*)d_in[3],  (const float*)d_in[7],  (const float*)d_in[11]};
    const float* b1[3] = {(const float*)d_in[4],  (const float*)d_in[8],  (const float*)d_in[12]};
    const float* w2[3] = {(const float*)d_in[5],  (const float*)d_in[9],  (const float*)d_in[13]};
    const float* b2[3] = {(const float*)d_in[6],  (const float*)d_in[10], (const float*)d_in[14]};
    const float* wl    = (const float*)d_in[15];
    const float* bl    = (const float*)d_in[16];

    char* p = (char*)d_ws;
    auto alloc = [&](size_t bytes) {
        char* r = p;
        p += (bytes + 255) & ~(size_t)255;
        return r;
    };
    int* off    = (int*)alloc((size_t)(N_NODES + 1) * 4);
    int* goff   = (int*)alloc((size_t)(NUM_GRAPHS + 1) * 4);
    int* histG  = (int*)alloc((size_t)(NB2 * PB) * 4);
    int* baseG  = (int*)alloc((size_t)(NB2 * PB + 1) * 4);
    int* bsum   = (int*)alloc((size_t)128 * 4);
    int* csr    = (int*)alloc((size_t)N_EDGES * 4);
    float* gsum = (float*)alloc((size_t)NUM_GRAPHS * 128 * 4);
    unsigned short* wts = (unsigned short*)alloc((size_t)6 * 16384 * 2);
    unsigned short* hA  = (unsigned short*)alloc((size_t)N_NODES * 128 * 2);
    unsigned short* hS  = (unsigned short*)alloc((size_t)N_NODES * 128 * 2);
    unsigned short* hB  = (unsigned short*)alloc((size_t)N_NODES * 128 * 2);
    uint64* ebuf = (uint64*)hS;   // alias: hS first written after CSR build completes

    hipMemsetAsync(gsum, 0, (size_t)NUM_GRAPHS * 128 * 4, stream);

    // ---- merged front: cast | wprep | p1 histogram ----
    k_front<<<NCAST + 6 + PB, 256, 0, stream>>>(x, hA,
        w1[0], w2[0], w1[1], w2[1], w1[2], w2[2], wts, ei + N_EDGES, histG);

    // ---- CSR build: block-binned counting sort, zero global atomics ----
    const int SCAN_N = NB2 * PB;                        // 39200
    const int SCAN_BLOCKS = (SCAN_N + 1023) / 1024;     // 39
    k_scan1<<<SCAN_BLOCKS, 256, 0, stream>>>(histG, baseG, bsum, SCAN_N);
    k_scan3b<<<SCAN_BLOCKS, 256, 0, stream>>>(baseG, bsum, SCAN_N);
    k_p3g<<<PB + 2, 512, 0, stream>>>(ei, baseG, ebuf, batch, goff);
    k_p4<<<NB2, 512, 0, stream>>>(ebuf, baseG, off, csr);

    unsigned short* wt1[3] = {wts,             wts + 2 * 16384, wts + 4 * 16384};
    unsigned short* wt2[3] = {wts + 1 * 16384, wts + 3 * 16384, wts + 5 * 16384};

    const int AGG_GRID = N_NODES / 4;                   // one wave per node: 25000 blocks
    const int MLP_GRID = (N_NODES + 63) / 64;           // 1563 blocks, 64 rows each

    // layer 0
    k_agg<<<AGG_GRID, 256, 0, stream>>>(hA, off, csr, hS);
    k_mlp<1><<<MLP_GRID, 256, 0, stream>>>(hS, wt1[0], b1[0], wt2[0], b2[0], hB);
    // layer 1
    k_agg<<<AGG_GRID, 256, 0, stream>>>(hB, off, csr, hS);
    k_mlp<1><<<MLP_GRID, 256, 0, stream>>>(hS, wt1[1], b1[1], wt2[1], b2[1], hA);
    // layer 2: agg -> mm1 -> per-graph pool of T (mm2 deferred to k_final)
    k_agg<<<AGG_GRID, 256, 0, stream>>>(hA, off, csr, hS);
    k_mlp2<<<MLP_GRID, 256, 0, stream>>>(hS, wt1[2], b1[2], batch, gsum);

    k_final<<<NUM_GRAPHS, 64, 0, stream>>>(gsum, goff, wt2[2], b2[2], wl, bl, (float*)d_out);
}